// Round 3
// baseline (96.755 us; speedup 1.0000x reference)
//
#include <hip/hip_runtime.h>
#include <hip/hip_cooperative_groups.h>
#include <math.h>

namespace cg = cooperative_groups;

constexpr float INV_B = 1.0f / 16384.0f;
constexpr float BN_EPS_C = 1e-5f;
constexpr int NUM_USERS_C = 1000000;

typedef __attribute__((ext_vector_type(8))) short bf16x8;
typedef __attribute__((ext_vector_type(4))) float f32x4;

__device__ inline unsigned short f2bf(float f) {
    union { float f; unsigned u; } v; v.f = f;
    unsigned r = v.u + 0x7FFFu + ((v.u >> 16) & 1u);   // RNE
    return (unsigned short)(r >> 16);
}
__device__ inline float bf2f(unsigned short h) {
    union { unsigned u; float f; } v; v.u = ((unsigned)h) << 16; return v.f;
}
__device__ inline bf16x8 pack8(float4 a, float4 b) {
    bf16x8 sv;
    sv[0] = (short)f2bf(a.x); sv[1] = (short)f2bf(a.y);
    sv[2] = (short)f2bf(a.z); sv[3] = (short)f2bf(a.w);
    sv[4] = (short)f2bf(b.x); sv[5] = (short)f2bf(b.y);
    sv[6] = (short)f2bf(b.z); sv[7] = (short)f2bf(b.w);
    return sv;
}
// swizzled byte offsets (XOR bits 4-6 with row&7 — bank-conflict-free ds_read_b128)
__device__ inline unsigned hswz(int row, int kb)   { return (unsigned)(row * 512 + (kb ^ ((row & 7) << 4))); }
__device__ inline unsigned swz256(int n, int kb)   { return (unsigned)(n * 256 + (kb ^ ((n & 7) << 4))); }
__device__ inline unsigned swz128(int n, int kb)   { return (unsigned)(n * 128 + (kb ^ ((n & 7) << 4))); }

// ---------------------------------------------------------------------------
// Fully fused Wide&Deep: 256 blocks x 64 batch rows, 256 threads (4 waves).
// h1 lives in LDS (bf16, swizzled); h2 lives in MFMA accumulators.
// BN batch stats via LDS reduce + global atomics + grid.sync().
// ---------------------------------------------------------------------------
__global__ __launch_bounds__(256, 1) void wd_fused(
    const int* __restrict__ ui, const int* __restrict__ ii,
    const float* __restrict__ wide_w, const float* __restrict__ wide_b,
    const float* __restrict__ utab, const float* __restrict__ itab,
    const float* __restrict__ W1, const float* __restrict__ b1,
    const float* __restrict__ g1, const float* __restrict__ be1,
    const float* __restrict__ W2, const float* __restrict__ b2,
    const float* __restrict__ g2, const float* __restrict__ be2,
    const float* __restrict__ W3, const float* __restrict__ b3,
    float* __restrict__ sum1, float* __restrict__ sumsq1,
    float* __restrict__ sum2, float* __restrict__ sumsq2,
    float* __restrict__ out)
{
    __shared__ unsigned short Hs[64 * 256];    // 32 KB: X then h1, pitch 512 B
    __shared__ unsigned short Wbuf[8192];      // 16 KB weight staging
    __shared__ float a1s[256], c1s[256];
    __shared__ float sstat[512];
    __shared__ float wide_s[64];
    __shared__ float af[128], cf[128];
    __shared__ float C2s;

    cg::grid_group grid = cg::this_grid();
    const int tid = threadIdx.x;
    const int row0 = blockIdx.x * 64;
    const int w = tid >> 6, lane = tid & 63, lr = lane & 15, lk = lane >> 4;

    // ---- phase 0: wide-path prefetch (latency hidden under GEMMs) ----
    if (tid < 64) {
        int r = row0 + tid;
        wide_s[tid] = wide_w[ui[r]] + wide_w[NUM_USERS_C + ii[r]];
    }

    // ---- phase 1: gather X (64 x 128) -> Hs bf16 ----
#pragma unroll
    for (int iter = 0; iter < 4; ++iter) {
        int idx = iter * 256 + tid;
        int row = idx >> 4, chunk = idx & 15;
        int gr = row0 + row;
        const float* src = (chunk < 8)
            ? utab + (size_t)ui[gr] * 64 + chunk * 8
            : itab + (size_t)ii[gr] * 64 + (chunk - 8) * 8;
        float4 va = ((const float4*)src)[0];
        float4 vb = ((const float4*)src)[1];
        *(bf16x8*)((char*)Hs + hswz(row, chunk * 16)) = pack8(va, vb);
    }
    __syncthreads();

    // ---- layer 1: M=64, N=256, K=128; wave = 16 rows x 256 cols ----
    bf16x8 a1[4];
#pragma unroll
    for (int kst = 0; kst < 4; ++kst)
        a1[kst] = *(const bf16x8*)((const char*)Hs + hswz(w * 16 + lr, kst * 64 + lk * 16));

    f32x4 acc1[16];
#pragma unroll
    for (int f = 0; f < 16; ++f) acc1[f] = (f32x4){0.f, 0.f, 0.f, 0.f};

#pragma unroll
    for (int cb = 0; cb < 4; ++cb) {           // N-chunks of 64 cols
        if (cb) __syncthreads();
#pragma unroll
        for (int iter = 0; iter < 4; ++iter) { // stage W1 chunk (64 n x 128 k)
            int idx = iter * 256 + tid;
            int n = idx >> 4, chunk = idx & 15;
            const float* src = W1 + (size_t)(cb * 64 + n) * 128 + chunk * 8;
            float4 va = ((const float4*)src)[0];
            float4 vb = ((const float4*)src)[1];
            *(bf16x8*)((char*)Wbuf + swz256(n, chunk * 16)) = pack8(va, vb);
        }
        __syncthreads();
#pragma unroll
        for (int kst = 0; kst < 4; ++kst) {
            bf16x8 b[4];
#pragma unroll
            for (int nj = 0; nj < 4; ++nj)
                b[nj] = *(const bf16x8*)((const char*)Wbuf + swz256(nj * 16 + lr, kst * 64 + lk * 16));
#pragma unroll
            for (int nj = 0; nj < 4; ++nj)
                acc1[cb * 4 + nj] = __builtin_amdgcn_mfma_f32_16x16x32_bf16(a1[kst], b[nj], acc1[cb * 4 + nj], 0, 0, 0);
        }
    }

    // ---- layer-1 epilogue: bias+ReLU+bf16 -> Hs; column sums ----
    __syncthreads();
    sstat[tid] = 0.f; sstat[256 + tid] = 0.f;
    __syncthreads();
#pragma unroll
    for (int f = 0; f < 16; ++f) {
        int col = f * 16 + lr;
        float bias = b1[col];
        float s = 0.f, q = 0.f;
#pragma unroll
        for (int reg = 0; reg < 4; ++reg) {
            int rl = w * 16 + lk * 4 + reg;
            float v = fmaxf(acc1[f][reg] + bias, 0.f);
            unsigned short hb = f2bf(v);
            float vr = bf2f(hb);
            s += vr; q += vr * vr;
            *(unsigned short*)((char*)Hs + hswz(rl, col * 2)) = hb;
        }
        s += __shfl_xor(s, 16); s += __shfl_xor(s, 32);
        q += __shfl_xor(q, 16); q += __shfl_xor(q, 32);
        if (lk == 0) { atomicAdd(&sstat[col], s); atomicAdd(&sstat[256 + col], q); }
    }
    __syncthreads();
    atomicAdd(&sum1[tid], sstat[tid]);
    atomicAdd(&sumsq1[tid], sstat[256 + tid]);

    grid.sync();

    // ---- BN1 affine, applied in place to Hs ----
    {
        float s  = __hip_atomic_load(&sum1[tid],   __ATOMIC_RELAXED, __HIP_MEMORY_SCOPE_AGENT);
        float qq = __hip_atomic_load(&sumsq1[tid], __ATOMIC_RELAXED, __HIP_MEMORY_SCOPE_AGENT);
        float mu = s * INV_B;
        float var = fmaf(qq, INV_B, -mu * mu);
        float rs = rsqrtf(var + BN_EPS_C);
        float a = g1[tid] * rs;
        a1s[tid] = a;
        c1s[tid] = fmaf(-mu, a, be1[tid]);
    }
    __syncthreads();
#pragma unroll
    for (int iter = 0; iter < 8; ++iter) {
        int idx = iter * 256 + tid;
        int row = idx >> 5, chunk = idx & 31;
        char* p = (char*)Hs + hswz(row, chunk * 16);
        bf16x8 hv = *(bf16x8*)p;
        int k0 = chunk * 8;
        bf16x8 sv;
#pragma unroll
        for (int j = 0; j < 8; ++j) {
            float fv = bf2f((unsigned short)hv[j]);
            fv = fmaf(a1s[k0 + j], fv, c1s[k0 + j]);
            sv[j] = (short)f2bf(fv);
        }
        *(bf16x8*)p = sv;
    }

    // ---- layer 2: M=64, N=128, K=256; wave = 16 rows x 128 cols ----
    f32x4 acc2[8];
#pragma unroll
    for (int nj = 0; nj < 8; ++nj) acc2[nj] = (f32x4){0.f, 0.f, 0.f, 0.f};

#pragma unroll
    for (int kt = 0; kt < 4; ++kt) {           // K-chunks of 64
        __syncthreads();
#pragma unroll
        for (int iter = 0; iter < 4; ++iter) { // stage W2 chunk (128 n x 64 k)
            int idx = iter * 256 + tid;
            int n = idx >> 3, chunk = idx & 7;
            const float* src = W2 + (size_t)n * 256 + kt * 64 + chunk * 8;
            float4 va = ((const float4*)src)[0];
            float4 vb = ((const float4*)src)[1];
            *(bf16x8*)((char*)Wbuf + swz128(n, chunk * 16)) = pack8(va, vb);
        }
        __syncthreads();
#pragma unroll
        for (int ks = 0; ks < 2; ++ks) {
            bf16x8 a2 = *(const bf16x8*)((const char*)Hs + hswz(w * 16 + lr, kt * 128 + ks * 64 + lk * 16));
            bf16x8 b[8];
#pragma unroll
            for (int nj = 0; nj < 8; ++nj)
                b[nj] = *(const bf16x8*)((const char*)Wbuf + swz128(nj * 16 + lr, ks * 64 + lk * 16));
#pragma unroll
            for (int nj = 0; nj < 8; ++nj)
                acc2[nj] = __builtin_amdgcn_mfma_f32_16x16x32_bf16(a2, b[nj], acc2[nj], 0, 0, 0);
        }
    }

    // ---- layer-2 epilogue: bias+ReLU in registers; column sums ----
    __syncthreads();
    sstat[tid] = 0.f;
    __syncthreads();
#pragma unroll
    for (int nj = 0; nj < 8; ++nj) {
        int col = nj * 16 + lr;
        float bias = b2[col];
        float s = 0.f, q = 0.f;
#pragma unroll
        for (int reg = 0; reg < 4; ++reg) {
            float v = fmaxf(acc2[nj][reg] + bias, 0.f);
            acc2[nj][reg] = v;
            s += v; q += v * v;
        }
        s += __shfl_xor(s, 16); s += __shfl_xor(s, 32);
        q += __shfl_xor(q, 16); q += __shfl_xor(q, 32);
        if (lk == 0) { atomicAdd(&sstat[col], s); atomicAdd(&sstat[128 + col], q); }
    }
    __syncthreads();
    if (tid < 128) {
        atomicAdd(&sum2[tid], sstat[tid]);
        atomicAdd(&sumsq2[tid], sstat[128 + tid]);
    }

    grid.sync();

    // ---- BN2 folded into W3; final dot + wide + sigmoid ----
    if (tid < 128) {
        float s  = __hip_atomic_load(&sum2[tid],   __ATOMIC_RELAXED, __HIP_MEMORY_SCOPE_AGENT);
        float qq = __hip_atomic_load(&sumsq2[tid], __ATOMIC_RELAXED, __HIP_MEMORY_SCOPE_AGENT);
        float mu = s * INV_B;
        float var = fmaf(qq, INV_B, -mu * mu);
        float rs = rsqrtf(var + BN_EPS_C);
        float a = g2[tid] * rs;
        float c = fmaf(-mu, a, be2[tid]);
        float w3 = W3[tid];
        af[tid] = a * w3;
        cf[tid] = c * w3;
    }
    __syncthreads();
    if (tid < 64) {
        float x = cf[tid] + cf[tid + 64];
        x += __shfl_xor(x, 1);  x += __shfl_xor(x, 2);  x += __shfl_xor(x, 4);
        x += __shfl_xor(x, 8);  x += __shfl_xor(x, 16); x += __shfl_xor(x, 32);
        if (tid == 0) C2s = x;
    }
    __syncthreads();

    float part[4] = {0.f, 0.f, 0.f, 0.f};
#pragma unroll
    for (int nj = 0; nj < 8; ++nj) {
        float a_ = af[nj * 16 + lr];
#pragma unroll
        for (int reg = 0; reg < 4; ++reg)
            part[reg] = fmaf(a_, acc2[nj][reg], part[reg]);
    }
#pragma unroll
    for (int reg = 0; reg < 4; ++reg) {
        part[reg] += __shfl_xor(part[reg], 1);
        part[reg] += __shfl_xor(part[reg], 2);
        part[reg] += __shfl_xor(part[reg], 4);
        part[reg] += __shfl_xor(part[reg], 8);
    }
    if (lr == 0) {
        float base = C2s + b3[0] + wide_b[0];
#pragma unroll
        for (int reg = 0; reg < 4; ++reg) {
            int rl = w * 16 + lk * 4 + reg;
            float logit = part[reg] + base + wide_s[rl];
            out[row0 + rl] = 1.f / (1.f + expf(-logit));
        }
    }
}

extern "C" void kernel_launch(void* const* d_in, const int* in_sizes, int n_in,
                              void* d_out, int out_size, void* d_ws, size_t ws_size,
                              hipStream_t stream)
{
    const int*   ui     = (const int*)d_in[0];
    const int*   ii     = (const int*)d_in[1];
    const float* wide_w = (const float*)d_in[2];
    const float* wide_b = (const float*)d_in[3];
    const float* utab   = (const float*)d_in[4];
    const float* itab   = (const float*)d_in[5];
    const float* W1     = (const float*)d_in[6];
    const float* b1     = (const float*)d_in[7];
    const float* g1     = (const float*)d_in[8];
    const float* be1    = (const float*)d_in[9];
    const float* W2     = (const float*)d_in[10];
    const float* b2     = (const float*)d_in[11];
    const float* g2     = (const float*)d_in[12];
    const float* be2    = (const float*)d_in[13];
    const float* W3     = (const float*)d_in[14];
    const float* b3     = (const float*)d_in[15];
    float* outp = (float*)d_out;

    float* stats = (float*)d_ws;
    float* sum1   = stats;
    float* sumsq1 = stats + 256;
    float* sum2   = stats + 512;
    float* sumsq2 = stats + 640;

    hipMemsetAsync(stats, 0, 768 * sizeof(float), stream);

    void* args[] = {
        (void*)&ui, (void*)&ii, (void*)&wide_w, (void*)&wide_b,
        (void*)&utab, (void*)&itab, (void*)&W1, (void*)&b1,
        (void*)&g1, (void*)&be1, (void*)&W2, (void*)&b2,
        (void*)&g2, (void*)&be2, (void*)&W3, (void*)&b3,
        (void*)&sum1, (void*)&sumsq1, (void*)&sum2, (void*)&sumsq2,
        (void*)&outp
    };
    hipLaunchCooperativeKernel((const void*)wd_fused, dim3(256), dim3(256), args, 0, stream);
}

// Round 4
// 37.164 us; speedup vs baseline: 2.6035x; 2.6035x over previous
//
#include <hip/hip_runtime.h>
#include <math.h>

constexpr float INV_B = 1.0f / 16384.0f;
constexpr float BN_EPS_C = 1e-5f;
constexpr int NUM_USERS_C = 1000000;

typedef __attribute__((ext_vector_type(8))) short bf16x8;
typedef __attribute__((ext_vector_type(4))) float f32x4;

__device__ inline unsigned short f2bf(float f) {
    union { float f; unsigned u; } v; v.f = f;
    unsigned r = v.u + 0x7FFFu + ((v.u >> 16) & 1u);   // RNE
    return (unsigned short)(r >> 16);
}
__device__ inline float bf2f(unsigned short h) {
    union { unsigned u; float f; } v; v.u = ((unsigned)h) << 16; return v.f;
}
__device__ inline bf16x8 pack8(float4 a, float4 b) {
    bf16x8 sv;
    sv[0] = (short)f2bf(a.x); sv[1] = (short)f2bf(a.y);
    sv[2] = (short)f2bf(a.z); sv[3] = (short)f2bf(a.w);
    sv[4] = (short)f2bf(b.x); sv[5] = (short)f2bf(b.y);
    sv[6] = (short)f2bf(b.z); sv[7] = (short)f2bf(b.w);
    return sv;
}
// XOR swizzles: pitch-256B and pitch-512B row-major bf16 tiles
__device__ inline unsigned swz256(int r, int kb) { return (unsigned)(r * 256 + (kb ^ ((r & 7) << 4))); }
__device__ inline unsigned swz512(int r, int kb) { return (unsigned)(r * 512 + (kb ^ ((r & 7) << 4))); }

// ---------------------------------------------------------------------------
// K1: gather X(64x128 bf16), GEMM vs W1^T (all 256 cols), +b1, ReLU ->
//     h1s tile-linear swizzled bf16; column sum/sq partials -> part1[8 reps].
// 512 threads = 8 waves (wm 0..3 rows, wn 0..1 col-half of 128-col pair).
// ---------------------------------------------------------------------------
__global__ __launch_bounds__(512, 4) void wd_k1(
    const int* __restrict__ ui, const int* __restrict__ ii,
    const float* __restrict__ utab, const float* __restrict__ itab,
    const float* __restrict__ W1, const float* __restrict__ b1,
    unsigned short* __restrict__ h1s, float* __restrict__ part1)
{
    __shared__ char smem[49152];       // Xs 16K | Wb 32K ; reused as 32K bounce
    __shared__ float sstat[512];
    char* Xs = smem;
    char* Wb = smem + 16384;

    const int tid = threadIdx.x, bid = blockIdx.x, row0 = bid * 64;
    const int w = tid >> 6, lane = tid & 63, lr = lane & 15, lk = lane >> 4;
    const int wm = w >> 1, wn = w & 1;

    // stage X: 64 rows x 128 k (bf16), gather + convert
#pragma unroll
    for (int it = 0; it < 2; ++it) {
        int idx = it * 512 + tid, row = idx >> 4, kc = idx & 15;
        const float* src = (kc < 8)
            ? utab + (size_t)ui[row0 + row] * 64 + kc * 8
            : itab + (size_t)ii[row0 + row] * 64 + (kc - 8) * 8;
        float4 a = ((const float4*)src)[0];
        float4 b = ((const float4*)src)[1];
        *(bf16x8*)(Xs + swz256(row, kc * 16)) = pack8(a, b);
    }
    // stage W pair 0 (cols 0..127)
#pragma unroll
    for (int it = 0; it < 4; ++it) {
        int idx = it * 512 + tid, n = idx >> 4, kc = idx & 15;
        const float* src = W1 + (size_t)n * 128 + kc * 8;
        float4 a = ((const float4*)src)[0];
        float4 b = ((const float4*)src)[1];
        *(bf16x8*)(Wb + swz256(n, kc * 16)) = pack8(a, b);
    }
    __syncthreads();

    bf16x8 a1[4];
#pragma unroll
    for (int kst = 0; kst < 4; ++kst)
        a1[kst] = *(const bf16x8*)(Xs + swz256(wm * 16 + lr, kst * 64 + lk * 16));

    f32x4 acc[8];
#pragma unroll
    for (int f = 0; f < 8; ++f) acc[f] = (f32x4){0.f, 0.f, 0.f, 0.f};

#pragma unroll
    for (int p = 0; p < 2; ++p) {
        if (p) {
            __syncthreads();
#pragma unroll
            for (int it = 0; it < 4; ++it) {
                int idx = it * 512 + tid, n = idx >> 4, kc = idx & 15;
                const float* src = W1 + (size_t)(128 + n) * 128 + kc * 8;
                float4 a = ((const float4*)src)[0];
                float4 b = ((const float4*)src)[1];
                *(bf16x8*)(Wb + swz256(n, kc * 16)) = pack8(a, b);
            }
            __syncthreads();
        }
#pragma unroll
        for (int kst = 0; kst < 4; ++kst) {
            bf16x8 b[4];
#pragma unroll
            for (int nj = 0; nj < 4; ++nj)
                b[nj] = *(const bf16x8*)(Wb + swz256(wn * 64 + nj * 16 + lr, kst * 64 + lk * 16));
#pragma unroll
            for (int nj = 0; nj < 4; ++nj)
                acc[p * 4 + nj] = __builtin_amdgcn_mfma_f32_16x16x32_bf16(a1[kst], b[nj], acc[p * 4 + nj], 0, 0, 0);
        }
    }
    __syncthreads();

    sstat[tid] = 0.f;
    float s_[8], q_[8];
#pragma unroll
    for (int f = 0; f < 8; ++f) { s_[f] = 0.f; q_[f] = 0.f; }
#pragma unroll
    for (int f = 0; f < 8; ++f) {
        int p = f >> 2, nj = f & 3;
        int col = p * 128 + wn * 64 + nj * 16 + lr;
        float bias = b1[col];
#pragma unroll
        for (int reg = 0; reg < 4; ++reg) {
            int rl = wm * 16 + lk * 4 + reg;
            float v = fmaxf(acc[f][reg] + bias, 0.f);
            unsigned short hb = f2bf(v);
            float vr = bf2f(hb);
            s_[f] += vr; q_[f] += vr * vr;
            *(unsigned short*)(smem + swz512(rl, col * 2)) = hb;   // bounce (swizzled tile)
        }
    }
    __syncthreads();
#pragma unroll
    for (int f = 0; f < 8; ++f) {
        int p = f >> 2, nj = f & 3;
        int col = p * 128 + wn * 64 + nj * 16 + lr;
        float s = s_[f], q = q_[f];
        s += __shfl_xor(s, 16); s += __shfl_xor(s, 32);
        q += __shfl_xor(q, 16); q += __shfl_xor(q, 32);
        if (lk == 0) { atomicAdd(&sstat[col], s); atomicAdd(&sstat[256 + col], q); }
    }
    __syncthreads();
    atomicAdd(&part1[(size_t)(bid & 7) * 512 + tid], sstat[tid]);
    // dump tile-linear (32 KB)
#pragma unroll
    for (int it = 0; it < 4; ++it) {
        int idx = it * 512 + tid;
        *(bf16x8*)(h1s + (size_t)bid * 16384 + idx * 8) = *(const bf16x8*)(smem + idx * 16);
    }
}

// ---------------------------------------------------------------------------
// K2: A-tile = raw h1s copy (pre-swizzled, no VALU); BN1 folded into W2/b2:
//     W2' = a1 (.) W2 (bf16), b2' = b2 + W2 c1 (f32). GEMM -> ReLU -> h2s
//     tile-linear bf16; stats -> part2[8 reps].
// ---------------------------------------------------------------------------
__global__ __launch_bounds__(512, 4) void wd_k2(
    const unsigned short* __restrict__ h1s, const float* __restrict__ part1,
    const float* __restrict__ g1, const float* __restrict__ be1,
    const float* __restrict__ W2, const float* __restrict__ b2,
    unsigned short* __restrict__ h2s, float* __restrict__ part2)
{
    __shared__ char smem[49152];       // As 32K | Wb 16K (Wb reused as bounce)
    __shared__ float a1s[256], c1s[256], b2p[128], sstat[256];
    char* As = smem;
    char* Wb = smem + 32768;

    const int tid = threadIdx.x, bid = blockIdx.x;
    const int w = tid >> 6, lane = tid & 63, lr = lane & 15, lk = lane >> 4;
    const int wm = w >> 1, wn = w & 1;

    // A-tile: pure copy (layout already LDS-ready)
#pragma unroll
    for (int it = 0; it < 4; ++it) {
        int idx = it * 512 + tid;
        *(bf16x8*)(As + idx * 16) = *(const bf16x8*)(h1s + (size_t)bid * 16384 + idx * 8);
    }
    // BN1 affine coefficients from 8 replicas
    if (tid < 256) {
        float s = 0.f, q = 0.f;
#pragma unroll
        for (int r = 0; r < 8; ++r) { s += part1[r * 512 + tid]; q += part1[r * 512 + 256 + tid]; }
        float mu = s * INV_B;
        float var = fmaf(q, INV_B, -mu * mu);
        float rs = rsqrtf(var + BN_EPS_C);
        float a = g1[tid] * rs;
        a1s[tid] = a;
        c1s[tid] = fmaf(-mu, a, be1[tid]);
    }
    __syncthreads();
    // b2' = b2 + W2 . c1  (f32, 4 lanes per output row)
    {
        int n = tid >> 2, q4 = tid & 3;
        const float* wrow = W2 + (size_t)n * 256 + q4 * 64;
        const float* cp = &c1s[q4 * 64];
        float t = 0.f;
#pragma unroll
        for (int j = 0; j < 16; ++j) {
            float4 wv = *(const float4*)(wrow + j * 4);
            t += wv.x * cp[j * 4 + 0] + wv.y * cp[j * 4 + 1] + wv.z * cp[j * 4 + 2] + wv.w * cp[j * 4 + 3];
        }
        t += __shfl_xor(t, 1); t += __shfl_xor(t, 2);
        if (q4 == 0) b2p[n] = b2[n] + t;
    }

    bf16x8 a2[8];
#pragma unroll
    for (int kst = 0; kst < 8; ++kst)
        a2[kst] = *(const bf16x8*)(As + swz512(wm * 16 + lr, kst * 64 + lk * 16));

    f32x4 acc[4];
#pragma unroll
    for (int c = 0; c < 4; ++c) acc[c] = (f32x4){0.f, 0.f, 0.f, 0.f};

    // stage chunk 0 (32 n x 256 k), W2 scaled by a1
#pragma unroll
    for (int it = 0; it < 2; ++it) {
        int idx = it * 512 + tid, n = idx >> 5, kc = idx & 31;
        const float* src = W2 + (size_t)n * 256 + kc * 8;
        const float* ap = &a1s[kc * 8];
        float4 a = ((const float4*)src)[0];
        float4 b = ((const float4*)src)[1];
        a.x *= ap[0]; a.y *= ap[1]; a.z *= ap[2]; a.w *= ap[3];
        b.x *= ap[4]; b.y *= ap[5]; b.z *= ap[6]; b.w *= ap[7];
        *(bf16x8*)(Wb + swz512(n, kc * 16)) = pack8(a, b);
    }
    __syncthreads();

    for (int c = 0; c < 4; ++c) {
#pragma unroll
        for (int kst = 0; kst < 8; ++kst) {
            bf16x8 bfr = *(const bf16x8*)(Wb + swz512(wn * 16 + lr, kst * 64 + lk * 16));
            acc[c] = __builtin_amdgcn_mfma_f32_16x16x32_bf16(a2[kst], bfr, acc[c], 0, 0, 0);
        }
        __syncthreads();
        if (c < 3) {
#pragma unroll
            for (int it = 0; it < 2; ++it) {
                int idx = it * 512 + tid, n = idx >> 5, kc = idx & 31;
                const float* src = W2 + (size_t)((c + 1) * 32 + n) * 256 + kc * 8;
                const float* ap = &a1s[kc * 8];
                float4 a = ((const float4*)src)[0];
                float4 b = ((const float4*)src)[1];
                a.x *= ap[0]; a.y *= ap[1]; a.z *= ap[2]; a.w *= ap[3];
                b.x *= ap[4]; b.y *= ap[5]; b.z *= ap[6]; b.w *= ap[7];
                *(bf16x8*)(Wb + swz512(n, kc * 16)) = pack8(a, b);
            }
            __syncthreads();
        }
    }

    // epilogue
    if (tid < 256) sstat[tid] = 0.f;
    float s_[4], q_[4];
#pragma unroll
    for (int c = 0; c < 4; ++c) { s_[c] = 0.f; q_[c] = 0.f; }
#pragma unroll
    for (int c = 0; c < 4; ++c) {
        int col = c * 32 + wn * 16 + lr;
        float bias = b2p[col];
#pragma unroll
        for (int reg = 0; reg < 4; ++reg) {
            int rl = wm * 16 + lk * 4 + reg;
            float v = fmaxf(acc[c][reg] + bias, 0.f);
            unsigned short hb = f2bf(v);
            float vr = bf2f(hb);
            s_[c] += vr; q_[c] += vr * vr;
            *(unsigned short*)(Wb + swz256(rl, col * 2)) = hb;   // bounce 16 KB
        }
    }
    __syncthreads();
#pragma unroll
    for (int c = 0; c < 4; ++c) {
        int col = c * 32 + wn * 16 + lr;
        float s = s_[c], q = q_[c];
        s += __shfl_xor(s, 16); s += __shfl_xor(s, 32);
        q += __shfl_xor(q, 16); q += __shfl_xor(q, 32);
        if (lk == 0) { atomicAdd(&sstat[col], s); atomicAdd(&sstat[128 + col], q); }
    }
    __syncthreads();
    if (tid < 256) atomicAdd(&part2[(size_t)(bid & 7) * 256 + tid], sstat[tid]);
#pragma unroll
    for (int it = 0; it < 2; ++it) {
        int idx = it * 512 + tid;
        *(bf16x8*)(h2s + (size_t)bid * 8192 + idx * 8) = *(const bf16x8*)(Wb + idx * 16);
    }
}

// ---------------------------------------------------------------------------
// K3: BN2 folded into W3; per-row dot on bf16 h2s (swizzle-aware reads)
//     + wide gather + sigmoid.
// ---------------------------------------------------------------------------
__global__ __launch_bounds__(256, 2) void wd_k3(
    const int* __restrict__ ui, const int* __restrict__ ii,
    const float* __restrict__ wide_w, const float* __restrict__ wide_b,
    const unsigned short* __restrict__ h2s, const float* __restrict__ part2,
    const float* __restrict__ g2, const float* __restrict__ be2,
    const float* __restrict__ W3, const float* __restrict__ b3,
    float* __restrict__ out)
{
    __shared__ float af[128], cf[128];
    const int tid = threadIdx.x, bid = blockIdx.x;
    const int r = tid >> 2, kq = tid & 3;
    const int row = bid * 64 + r;

    float wide = 0.f;
    if (kq == 0) wide = wide_w[ui[row]] + wide_w[NUM_USERS_C + ii[row]];

    if (tid < 128) {
        float s = 0.f, q = 0.f;
#pragma unroll
        for (int rr = 0; rr < 8; ++rr) { s += part2[rr * 256 + tid]; q += part2[rr * 256 + 128 + tid]; }
        float mu = s * INV_B;
        float var = fmaf(q, INV_B, -mu * mu);
        float rs = rsqrtf(var + BN_EPS_C);
        float a = g2[tid] * rs;
        float c = fmaf(-mu, a, be2[tid]);
        float w3 = W3[tid];
        af[tid] = a * w3;
        cf[tid] = c * w3;
    }
    __syncthreads();

    const char* tbase = (const char*)h2s + (size_t)bid * 16384;
    float acc = 0.f;
#pragma unroll
    for (int j = 0; j < 4; ++j) {
        int kb = (kq * 64 + j * 16) ^ ((r & 7) << 4);
        bf16x8 hv = *(const bf16x8*)(tbase + r * 256 + kb);
#pragma unroll
        for (int e = 0; e < 8; ++e) {
            float h = bf2f((unsigned short)hv[e]);
            int k = kq * 32 + j * 8 + e;
            acc += fmaf(h, af[k], cf[k]);
        }
    }
    acc += __shfl_xor(acc, 1);
    acc += __shfl_xor(acc, 2);
    if (kq == 0) {
        float logit = acc + b3[0] + wide_b[0] + wide;
        out[row] = 1.f / (1.f + expf(-logit));
    }
}

extern "C" void kernel_launch(void* const* d_in, const int* in_sizes, int n_in,
                              void* d_out, int out_size, void* d_ws, size_t ws_size,
                              hipStream_t stream)
{
    const int*   ui     = (const int*)d_in[0];
    const int*   ii     = (const int*)d_in[1];
    const float* wide_w = (const float*)d_in[2];
    const float* wide_b = (const float*)d_in[3];
    const float* utab   = (const float*)d_in[4];
    const float* itab   = (const float*)d_in[5];
    const float* W1     = (const float*)d_in[6];
    const float* b1     = (const float*)d_in[7];
    const float* g1     = (const float*)d_in[8];
    const float* be1    = (const float*)d_in[9];
    const float* W2     = (const float*)d_in[10];
    const float* b2     = (const float*)d_in[11];
    const float* g2     = (const float*)d_in[12];
    const float* be2    = (const float*)d_in[13];
    const float* W3     = (const float*)d_in[14];
    const float* b3     = (const float*)d_in[15];
    float* outp = (float*)d_out;

    char* base = (char*)d_ws;
    float* part1 = (float*)base;                       // 8 * 512 f32
    float* part2 = (float*)(base + 4096 * 4);          // 8 * 256 f32
    unsigned short* h1s = (unsigned short*)(base + 4096 * 4 + 2048 * 4);   // 256 tiles * 32 KB
    unsigned short* h2s = (unsigned short*)(base + 4096 * 4 + 2048 * 4 + (size_t)256 * 32768);

    hipMemsetAsync(part1, 0, (4096 + 2048) * sizeof(float), stream);

    wd_k1<<<256, 512, 0, stream>>>(ui, ii, utab, itab, W1, b1, h1s, part1);
    wd_k2<<<256, 512, 0, stream>>>(h1s, part1, g1, be1, W2, b2, h2s, part2);
    wd_k3<<<256, 256, 0, stream>>>(ui, ii, wide_w, wide_b, h2s, part2, g2, be2, W3, b3, outp);
}

// Round 5
// 33.822 us; speedup vs baseline: 2.8607x; 1.0988x over previous
//
#include <hip/hip_runtime.h>
#include <math.h>

constexpr float INV_B = 1.0f / 16384.0f;
constexpr float BN_EPS_C = 1e-5f;
constexpr int NUM_USERS_C = 1000000;

typedef __attribute__((ext_vector_type(8))) short bf16x8;
typedef __attribute__((ext_vector_type(4))) float f32x4;

__device__ inline unsigned short f2bf(float f) {
    union { float f; unsigned u; } v; v.f = f;
    unsigned r = v.u + 0x7FFFu + ((v.u >> 16) & 1u);   // RNE
    return (unsigned short)(r >> 16);
}
__device__ inline float bf2f(unsigned short h) {
    union { unsigned u; float f; } v; v.u = ((unsigned)h) << 16; return v.f;
}
__device__ inline bf16x8 pack8(float4 a, float4 b) {
    bf16x8 sv;
    sv[0] = (short)f2bf(a.x); sv[1] = (short)f2bf(a.y);
    sv[2] = (short)f2bf(a.z); sv[3] = (short)f2bf(a.w);
    sv[4] = (short)f2bf(b.x); sv[5] = (short)f2bf(b.y);
    sv[6] = (short)f2bf(b.z); sv[7] = (short)f2bf(b.w);
    return sv;
}
// XOR swizzle for pitch-256B row-major bf16 tiles (bank-conflict-free b128)
__device__ inline unsigned swz256(int r, int kb) { return (unsigned)(r * 256 + (kb ^ ((r & 7) << 4))); }

// ---------------------------------------------------------------------------
// K0: one-time weight conversion f32 -> bf16 pre-swizzled LDS-image layout,
//     plus zeroing of the stat replica buffers (absorbs the memset).
// img1: W1 as [256 n][256B k] swizzled. img2: W2 as 2 k-halves, each
//       [128 n][256B] swizzled (half h covers k in [128h,128h+128)).
// ---------------------------------------------------------------------------
__global__ __launch_bounds__(256) void wd_k0(
    const float* __restrict__ W1, const float* __restrict__ W2,
    unsigned short* __restrict__ img1, unsigned short* __restrict__ img2,
    float* __restrict__ stats)
{
    int t = blockIdx.x * 256 + threadIdx.x;        // grid 48*256 = 12288
    if (t < 12288) stats[t] = 0.f;
    if (t < 4096) {
        int a = t * 16, n = a >> 8, ks = a & 255;
        int k0 = (ks ^ ((n & 7) << 4)) >> 1;
        const float* src = W1 + (size_t)n * 128 + k0;
        float4 va = ((const float4*)src)[0];
        float4 vb = ((const float4*)src)[1];
        *(bf16x8*)((char*)img1 + a) = pack8(va, vb);
    } else if (t < 8192) {
        int tt = t - 4096;
        int a = tt * 16, h = a >> 15, rem = a & 32767, n = rem >> 8, ks = rem & 255;
        int kb = ks ^ ((n & 7) << 4);
        int k0 = h * 128 + (kb >> 1);
        const float* src = W2 + (size_t)n * 256 + k0;
        float4 va = ((const float4*)src)[0];
        float4 vb = ((const float4*)src)[1];
        *(bf16x8*)((char*)img2 + a) = pack8(va, vb);
    }
}

// ---------------------------------------------------------------------------
// K1: 512 blocks x 32 rows. Gather X(32x128 bf16), GEMM vs W1^T in two
//     128-col chunks (W = pure copy of img1), +b1, ReLU -> h1s image
//     ([32 r][512B] swizzled per tile); stats -> part1[16 replicas].
// ---------------------------------------------------------------------------
__global__ __launch_bounds__(512, 4) void wd_k1(
    const int* __restrict__ ui, const int* __restrict__ ii,
    const float* __restrict__ utab, const float* __restrict__ itab,
    const unsigned short* __restrict__ img1, const float* __restrict__ b1,
    unsigned short* __restrict__ h1s, float* __restrict__ part1)
{
    __shared__ char Xs[8192];        // 32 x 256B, swizzled
    __shared__ char Wb[32768];       // 128 n x 256B, swizzled; reused as bounce
    __shared__ float sstat[512];     // 256 sums | 256 sqs

    const int tid = threadIdx.x, bid = blockIdx.x, row0 = bid * 32;
    const int w = tid >> 6, lane = tid & 63, lr = lane & 15, lk = lane >> 4;
    const int wm = w >> 2, wn = w & 3;

    sstat[tid] = 0.f;

    // stage X: gather + convert (512 chunks = 1 per thread)
    {
        int row = tid >> 4, kc = tid & 15;
        const float* src = (kc < 8)
            ? utab + (size_t)ui[row0 + row] * 64 + kc * 8
            : itab + (size_t)ii[row0 + row] * 64 + (kc - 8) * 8;
        float4 a = ((const float4*)src)[0];
        float4 b = ((const float4*)src)[1];
        *(bf16x8*)(Xs + swz256(row, kc * 16)) = pack8(a, b);
    }
    // stage W chunk 0: pure 16B copy (image already LDS-ready)
#pragma unroll
    for (int it = 0; it < 4; ++it) {
        int idx = it * 512 + tid;
        *(bf16x8*)(Wb + idx * 16) = *(const bf16x8*)((const char*)img1 + idx * 16);
    }
    __syncthreads();

    bf16x8 a1[4];
#pragma unroll
    for (int kst = 0; kst < 4; ++kst)
        a1[kst] = *(const bf16x8*)(Xs + swz256(wm * 16 + lr, kst * 64 + lk * 16));

    for (int c = 0; c < 2; ++c) {
        if (c) {
            __syncthreads();
#pragma unroll
            for (int it = 0; it < 4; ++it) {
                int idx = it * 512 + tid;
                *(bf16x8*)(Wb + idx * 16) = *(const bf16x8*)((const char*)img1 + 32768 + idx * 16);
            }
            __syncthreads();
        }
        f32x4 acc[2];
        acc[0] = (f32x4){0.f, 0.f, 0.f, 0.f};
        acc[1] = (f32x4){0.f, 0.f, 0.f, 0.f};
#pragma unroll
        for (int kst = 0; kst < 4; ++kst) {
#pragma unroll
            for (int nj = 0; nj < 2; ++nj) {
                int n = wn * 32 + nj * 16 + lr;
                bf16x8 b = *(const bf16x8*)(Wb + n * 256 + ((kst * 64 + lk * 16) ^ ((n & 7) << 4)));
                acc[nj] = __builtin_amdgcn_mfma_f32_16x16x32_bf16(a1[kst], b, acc[nj], 0, 0, 0);
            }
        }
        __syncthreads();   // MFMA LDS reads done; Wb becomes bounce

        float s_[2], q_[2];
#pragma unroll
        for (int nj = 0; nj < 2; ++nj) {
            int colL = wn * 32 + nj * 16 + lr;
            float bias = b1[c * 128 + colL];
            s_[nj] = 0.f; q_[nj] = 0.f;
#pragma unroll
            for (int reg = 0; reg < 4; ++reg) {
                int rl = wm * 16 + lk * 4 + reg;
                float v = fmaxf(acc[nj][reg] + bias, 0.f);
                unsigned short hb = f2bf(v);
                float vr = bf2f(hb);
                s_[nj] += vr; q_[nj] += vr * vr;
                *(unsigned short*)(Wb + swz256(rl, colL * 2)) = hb;
            }
        }
        __syncthreads();   // bounce complete
        // dump chunk (8 KB, coalesced 16B) into h1s image: byte r*512 + c*256 + rem
        {
            int r = tid >> 4, rem = (tid & 15) * 16;
            bf16x8 v = *(const bf16x8*)(Wb + r * 256 + rem);
            *(bf16x8*)((char*)h1s + (size_t)bid * 16384 + r * 512 + c * 256 + rem) = v;
        }
#pragma unroll
        for (int nj = 0; nj < 2; ++nj) {
            float s = s_[nj], q = q_[nj];
            s += __shfl_xor(s, 16); s += __shfl_xor(s, 32);
            q += __shfl_xor(q, 16); q += __shfl_xor(q, 32);
            if (lk == 0) {
                int col = c * 128 + wn * 32 + nj * 16 + lr;
                atomicAdd(&sstat[col], s);
                atomicAdd(&sstat[256 + col], q);
            }
        }
    }
    __syncthreads();
    atomicAdd(&part1[(size_t)(bid & 15) * 512 + tid], sstat[tid]);
}

// ---------------------------------------------------------------------------
// K2: 512 blocks x 32 rows. BN1 applied during A staging (value transform,
//     layout preserved); W2 = pure copy of img2 in 2 k-halves. GEMM ->
//     +b2, ReLU -> h2s image ([32 r][256B] swizzled); stats -> part2.
// ---------------------------------------------------------------------------
__global__ __launch_bounds__(512, 4) void wd_k2(
    const unsigned short* __restrict__ h1s, const float* __restrict__ part1,
    const float* __restrict__ g1, const float* __restrict__ be1,
    const unsigned short* __restrict__ img2, const float* __restrict__ b2,
    unsigned short* __restrict__ h2s, float* __restrict__ part2)
{
    __shared__ char As[16384];       // 32 x 512B, swizzled (h1 image layout)
    __shared__ char Wb[32768];       // 128 n x 256B per k-half; reused as bounce
    __shared__ float a1s[256], c1s[256], sstat[256];

    const int tid = threadIdx.x, bid = blockIdx.x;
    const int w = tid >> 6, lane = tid & 63, lr = lane & 15, lk = lane >> 4;
    const int wm = w >> 2, wn = w & 3;

    // BN1 coefficients from 16 replicas
    if (tid < 256) {
        sstat[tid] = 0.f;
        float s = 0.f, q = 0.f;
#pragma unroll
        for (int r = 0; r < 16; ++r) { s += part1[r * 512 + tid]; q += part1[r * 512 + 256 + tid]; }
        float mu = s * INV_B;
        float var = fmaf(q, INV_B, -mu * mu);
        float rs = rsqrtf(var + BN_EPS_C);
        float a = g1[tid] * rs;
        a1s[tid] = a;
        c1s[tid] = fmaf(-mu, a, be1[tid]);
    }
    // stage W2 half 0 (independent of stats)
#pragma unroll
    for (int it = 0; it < 4; ++it) {
        int idx = it * 512 + tid;
        *(bf16x8*)(Wb + idx * 16) = *(const bf16x8*)((const char*)img2 + idx * 16);
    }
    __syncthreads();

    // stage A with BN affine (linear copy + value transform)
#pragma unroll
    for (int it = 0; it < 2; ++it) {
        int idx = it * 512 + tid;
        int a = idx * 16, r = a >> 9, ks = a & 511;
        int k0 = (ks ^ ((r & 7) << 4)) >> 1;
        bf16x8 hv = *(const bf16x8*)((const char*)h1s + (size_t)bid * 16384 + a);
        bf16x8 sv;
#pragma unroll
        for (int j = 0; j < 8; ++j) {
            float f = bf2f((unsigned short)hv[j]);
            f = fmaf(a1s[k0 + j], f, c1s[k0 + j]);
            sv[j] = (short)f2bf(f);
        }
        *(bf16x8*)(As + a) = sv;
    }
    __syncthreads();

    f32x4 acc[2];
    acc[0] = (f32x4){0.f, 0.f, 0.f, 0.f};
    acc[1] = (f32x4){0.f, 0.f, 0.f, 0.f};

    for (int h = 0; h < 2; ++h) {
        if (h) {
            __syncthreads();
#pragma unroll
            for (int it = 0; it < 4; ++it) {
                int idx = it * 512 + tid;
                *(bf16x8*)(Wb + idx * 16) = *(const bf16x8*)((const char*)img2 + 32768 + idx * 16);
            }
            __syncthreads();
        }
#pragma unroll
        for (int kst = 0; kst < 4; ++kst) {
            int r = wm * 16 + lr;
            bf16x8 a2 = *(const bf16x8*)(As + r * 512 + ((h * 256 + kst * 64 + lk * 16) ^ ((r & 7) << 4)));
#pragma unroll
            for (int nj = 0; nj < 2; ++nj) {
                int n = wn * 32 + nj * 16 + lr;
                bf16x8 b = *(const bf16x8*)(Wb + n * 256 + ((kst * 64 + lk * 16) ^ ((n & 7) << 4)));
                acc[nj] = __builtin_amdgcn_mfma_f32_16x16x32_bf16(a2, b, acc[nj], 0, 0, 0);
            }
        }
    }
    __syncthreads();   // Wb becomes bounce

    float s_[2], q_[2];
#pragma unroll
    for (int nj = 0; nj < 2; ++nj) {
        int col = wn * 32 + nj * 16 + lr;
        float bias = b2[col];
        s_[nj] = 0.f; q_[nj] = 0.f;
#pragma unroll
        for (int reg = 0; reg < 4; ++reg) {
            int rl = wm * 16 + lk * 4 + reg;
            float v = fmaxf(acc[nj][reg] + bias, 0.f);
            unsigned short hb = f2bf(v);
            float vr = bf2f(hb);
            s_[nj] += vr; q_[nj] += vr * vr;
            *(unsigned short*)(Wb + swz256(rl, col * 2)) = hb;
        }
    }
    __syncthreads();
    // dump h2 tile (8 KB, linear = image layout)
    *(bf16x8*)((char*)h2s + (size_t)bid * 8192 + tid * 16) = *(const bf16x8*)(Wb + tid * 16);
#pragma unroll
    for (int nj = 0; nj < 2; ++nj) {
        int col = wn * 32 + nj * 16 + lr;
        float s = s_[nj], q = q_[nj];
        s += __shfl_xor(s, 16); s += __shfl_xor(s, 32);
        q += __shfl_xor(q, 16); q += __shfl_xor(q, 32);
        if (lk == 0) { atomicAdd(&sstat[col], s); atomicAdd(&sstat[128 + col], q); }
    }
    __syncthreads();
    if (tid < 256) atomicAdd(&part2[(size_t)(bid & 15) * 256 + tid], sstat[tid]);
}

// ---------------------------------------------------------------------------
// K3: BN2 folded into W3; per-row dot on h2s image (swizzle-aware reads)
//     + wide gather + sigmoid. 256 blocks x 64 rows.
// ---------------------------------------------------------------------------
__global__ __launch_bounds__(256, 2) void wd_k3(
    const int* __restrict__ ui, const int* __restrict__ ii,
    const float* __restrict__ wide_w, const float* __restrict__ wide_b,
    const unsigned short* __restrict__ h2s, const float* __restrict__ part2,
    const float* __restrict__ g2, const float* __restrict__ be2,
    const float* __restrict__ W3, const float* __restrict__ b3,
    float* __restrict__ out)
{
    __shared__ float af[128], cf[128];
    const int tid = threadIdx.x, bid = blockIdx.x;
    const int r = tid >> 2, kq = tid & 3;
    const int row = bid * 64 + r;

    float wide = 0.f;
    if (kq == 0) wide = wide_w[ui[row]] + wide_w[NUM_USERS_C + ii[row]];

    if (tid < 128) {
        float s = 0.f, q = 0.f;
#pragma unroll
        for (int rr = 0; rr < 16; ++rr) { s += part2[rr * 256 + tid]; q += part2[rr * 256 + 128 + tid]; }
        float mu = s * INV_B;
        float var = fmaf(q, INV_B, -mu * mu);
        float rs = rsqrtf(var + BN_EPS_C);
        float a = g2[tid] * rs;
        float c = fmaf(-mu, a, be2[tid]);
        float w3 = W3[tid];
        af[tid] = a * w3;
        cf[tid] = c * w3;
    }
    __syncthreads();

    const int tile = row >> 5, rin = row & 31;
    const char* tb = (const char*)h2s + (size_t)tile * 8192 + rin * 256;
    float acc = 0.f;
#pragma unroll
    for (int j = 0; j < 4; ++j) {
        int ks = (kq * 64 + j * 16) ^ ((rin & 7) << 4);
        bf16x8 hv = *(const bf16x8*)(tb + ks);
#pragma unroll
        for (int e = 0; e < 8; ++e) {
            float h = bf2f((unsigned short)hv[e]);
            int k = kq * 32 + j * 8 + e;
            acc += fmaf(h, af[k], cf[k]);
        }
    }
    acc += __shfl_xor(acc, 1);
    acc += __shfl_xor(acc, 2);
    if (kq == 0) {
        float logit = acc + b3[0] + wide_b[0] + wide;
        out[row] = 1.f / (1.f + expf(-logit));
    }
}

extern "C" void kernel_launch(void* const* d_in, const int* in_sizes, int n_in,
                              void* d_out, int out_size, void* d_ws, size_t ws_size,
                              hipStream_t stream)
{
    const int*   ui     = (const int*)d_in[0];
    const int*   ii     = (const int*)d_in[1];
    const float* wide_w = (const float*)d_in[2];
    const float* wide_b = (const float*)d_in[3];
    const float* utab   = (const float*)d_in[4];
    const float* itab   = (const float*)d_in[5];
    const float* W1     = (const float*)d_in[6];
    const float* b1     = (const float*)d_in[7];
    const float* g1     = (const float*)d_in[8];
    const float* be1    = (const float*)d_in[9];
    const float* W2     = (const float*)d_in[10];
    const float* b2     = (const float*)d_in[11];
    const float* g2     = (const float*)d_in[12];
    const float* be2    = (const float*)d_in[13];
    const float* W3     = (const float*)d_in[14];
    const float* b3     = (const float*)d_in[15];
    float* outp = (float*)d_out;

    char* base = (char*)d_ws;
    float* part1 = (float*)base;                                   // 16*512 f32
    float* part2 = (float*)(base + 16 * 512 * 4);                  // 16*256 f32
    unsigned short* img1 = (unsigned short*)(base + 49152);        // 64 KB
    unsigned short* img2 = (unsigned short*)(base + 49152 + 65536);
    unsigned short* h1s  = (unsigned short*)(base + 49152 + 131072);              // 8 MB
    unsigned short* h2s  = (unsigned short*)(base + 49152 + 131072 + (size_t)512 * 16384);

    wd_k0<<<48, 256, 0, stream>>>(W1, W2, img1, img2, part1);
    wd_k1<<<512, 512, 0, stream>>>(ui, ii, utab, itab, img1, b1, h1s, part1);
    wd_k2<<<512, 512, 0, stream>>>(h1s, part1, g1, be1, img2, b2, h2s, part2);
    wd_k3<<<256, 256, 0, stream>>>(ui, ii, wide_w, wide_b, h2s, part2, g2, be2, W3, b3, outp);
}

// Round 6
// 28.989 us; speedup vs baseline: 3.3376x; 1.1667x over previous
//
#include <hip/hip_runtime.h>
#include <math.h>

constexpr float INV_B = 1.0f / 16384.0f;
constexpr float BN_EPS_C = 1e-5f;
constexpr int NUM_USERS_C = 1000000;

typedef __attribute__((ext_vector_type(8))) short bf16x8;
typedef __attribute__((ext_vector_type(4))) float f32x4;

__device__ inline unsigned short f2bf(float f) {
    union { float f; unsigned u; } v; v.f = f;
    unsigned r = v.u + 0x7FFFu + ((v.u >> 16) & 1u);   // RNE
    return (unsigned short)(r >> 16);
}
__device__ inline float bf2f(unsigned short h) {
    union { unsigned u; float f; } v; v.u = ((unsigned)h) << 16; return v.f;
}
__device__ inline bf16x8 pack8(float4 a, float4 b) {
    bf16x8 sv;
    sv[0] = (short)f2bf(a.x); sv[1] = (short)f2bf(a.y);
    sv[2] = (short)f2bf(a.z); sv[3] = (short)f2bf(a.w);
    sv[4] = (short)f2bf(b.x); sv[5] = (short)f2bf(b.y);
    sv[6] = (short)f2bf(b.z); sv[7] = (short)f2bf(b.w);
    return sv;
}
// XOR swizzles for pitch-256B / pitch-512B row-major bf16 tiles
__device__ inline unsigned swz256(int r, int kb) { return (unsigned)(r * 256 + (kb ^ ((r & 7) << 4))); }
__device__ inline unsigned swz512(int r, int kb) { return (unsigned)(r * 512 + (kb ^ ((r & 7) << 4))); }

// ---------------------------------------------------------------------------
// K0: one-time weight conversion f32 -> bf16 fragment-image layout, plus
//     zeroing of the stat replica buffers.
// img1: W1 as [256 n][256B k] swizzled. img2: W2 as 2 k-halves, each
//       [128 n][256B] swizzled (half h covers k in [128h,128h+128)).
// ---------------------------------------------------------------------------
__global__ __launch_bounds__(256) void wd_k0(
    const float* __restrict__ W1, const float* __restrict__ W2,
    unsigned short* __restrict__ img1, unsigned short* __restrict__ img2,
    float* __restrict__ stats)
{
    int t = blockIdx.x * 256 + threadIdx.x;        // grid 48*256 = 12288
    if (t < 12288) stats[t] = 0.f;
    if (t < 4096) {
        int a = t * 16, n = a >> 8, ks = a & 255;
        int k0 = (ks ^ ((n & 7) << 4)) >> 1;
        const float* src = W1 + (size_t)n * 128 + k0;
        float4 va = ((const float4*)src)[0];
        float4 vb = ((const float4*)src)[1];
        *(bf16x8*)((char*)img1 + a) = pack8(va, vb);
    } else if (t < 8192) {
        int tt = t - 4096;
        int a = tt * 16, h = a >> 15, rem = a & 32767, n = rem >> 8, ks = rem & 255;
        int kb = ks ^ ((n & 7) << 4);
        int k0 = h * 128 + (kb >> 1);
        const float* src = W2 + (size_t)n * 256 + k0;
        float4 va = ((const float4*)src)[0];
        float4 vb = ((const float4*)src)[1];
        *(bf16x8*)((char*)img2 + a) = pack8(va, vb);
    }
}

// ---------------------------------------------------------------------------
// K1: 512 blocks x 32 rows. B-fragments preloaded per-lane from img1 (no LDS
//     staging, no duplication: 8 waves cover all 256 cols). Gather X -> LDS,
//     GEMM, +b1, ReLU -> h1s image; stats -> part1[16 replicas]. 2 barriers.
// ---------------------------------------------------------------------------
__global__ __launch_bounds__(512, 4) void wd_k1(
    const int* __restrict__ ui, const int* __restrict__ ii,
    const float* __restrict__ utab, const float* __restrict__ itab,
    const unsigned short* __restrict__ img1, const float* __restrict__ b1,
    unsigned short* __restrict__ h1s, float* __restrict__ part1)
{
    __shared__ char Xs[8192];        // 32 x 256B, swizzled
    __shared__ char Bnc[16384];      // bounce: 32 x 512B, swizzled
    __shared__ float sstat[512];

    const int tid = threadIdx.x, bid = blockIdx.x, row0 = bid * 32;
    const int w = tid >> 6, lane = tid & 63, lr = lane & 15, lk = lane >> 4;

    // preload B fragments for this wave's 32 columns (issued first)
    bf16x8 bfr[2][4];
#pragma unroll
    for (int nj = 0; nj < 2; ++nj) {
        int n = w * 32 + nj * 16 + lr;
        const char* bp = (const char*)img1 + n * 256;
        int sx = (n & 7) << 4;
#pragma unroll
        for (int kst = 0; kst < 4; ++kst)
            bfr[nj][kst] = *(const bf16x8*)(bp + ((kst * 64 + lk * 16) ^ sx));
    }

    // stage X: gather + convert (1 chunk per thread)
    {
        int row = tid >> 4, kc = tid & 15;
        const float* src = (kc < 8)
            ? utab + (size_t)ui[row0 + row] * 64 + kc * 8
            : itab + (size_t)ii[row0 + row] * 64 + (kc - 8) * 8;
        float4 a = ((const float4*)src)[0];
        float4 b = ((const float4*)src)[1];
        *(bf16x8*)(Xs + swz256(row, kc * 16)) = pack8(a, b);
    }
    __syncthreads();

    f32x4 acc[2][2];
#pragma unroll
    for (int mi = 0; mi < 2; ++mi)
#pragma unroll
        for (int nj = 0; nj < 2; ++nj) acc[mi][nj] = (f32x4){0.f, 0.f, 0.f, 0.f};

#pragma unroll
    for (int kst = 0; kst < 4; ++kst) {
        int kb = kst * 64 + lk * 16;
        bf16x8 a0 = *(const bf16x8*)(Xs + swz256(lr, kb));
        bf16x8 a1v = *(const bf16x8*)(Xs + swz256(16 + lr, kb));
#pragma unroll
        for (int nj = 0; nj < 2; ++nj) {
            acc[0][nj] = __builtin_amdgcn_mfma_f32_16x16x32_bf16(a0, bfr[nj][kst], acc[0][nj], 0, 0, 0);
            acc[1][nj] = __builtin_amdgcn_mfma_f32_16x16x32_bf16(a1v, bfr[nj][kst], acc[1][nj], 0, 0, 0);
        }
    }

    // epilogue: bias + relu + bf16, bounce to Bnc, per-col stats
#pragma unroll
    for (int nj = 0; nj < 2; ++nj) {
        int col = w * 32 + nj * 16 + lr;
        float bias = b1[col];
        float s = 0.f, q = 0.f;
#pragma unroll
        for (int mi = 0; mi < 2; ++mi)
#pragma unroll
            for (int reg = 0; reg < 4; ++reg) {
                int rl = mi * 16 + lk * 4 + reg;
                float v = fmaxf(acc[mi][nj][reg] + bias, 0.f);
                unsigned short hb = f2bf(v);
                float vr = bf2f(hb);
                s += vr; q += vr * vr;
                *(unsigned short*)(Bnc + swz512(rl, col * 2)) = hb;
            }
        s += __shfl_xor(s, 16); s += __shfl_xor(s, 32);
        q += __shfl_xor(q, 16); q += __shfl_xor(q, 32);
        if (lk == 0) { sstat[col] = s; sstat[256 + col] = q; }   // unique writer per col
    }
    __syncthreads();

    // dump 16 KB tile (32B per thread, coalesced) + stats replica add
    {
        const char* s0 = Bnc + tid * 32;
        char* d0 = (char*)h1s + (size_t)bid * 16384 + tid * 32;
        *(bf16x8*)d0 = *(const bf16x8*)s0;
        *(bf16x8*)(d0 + 16) = *(const bf16x8*)(s0 + 16);
    }
    atomicAdd(&part1[(size_t)(bid & 15) * 512 + tid], sstat[tid]);
}

// ---------------------------------------------------------------------------
// K2: 512 blocks x 32 rows. B-fragments preloaded per-lane from img2; BN1
//     applied during A staging (value transform, layout preserved). GEMM ->
//     +b2, ReLU -> h2s image; stats -> part2. 3 barriers.
// ---------------------------------------------------------------------------
__global__ __launch_bounds__(512, 4) void wd_k2(
    const unsigned short* __restrict__ h1s, const float* __restrict__ part1,
    const float* __restrict__ g1, const float* __restrict__ be1,
    const unsigned short* __restrict__ img2, const float* __restrict__ b2,
    unsigned short* __restrict__ h2s, float* __restrict__ part2)
{
    __shared__ char As[16384];       // 32 x 512B, swizzled (h1 image layout)
    __shared__ char Bnc[8192];       // bounce: 32 x 256B, swizzled
    __shared__ float a1s[256], c1s[256], sstat[256];

    const int tid = threadIdx.x, bid = blockIdx.x;
    const int w = tid >> 6, lane = tid & 63, lr = lane & 15, lk = lane >> 4;
    const int n = w * 16 + lr;            // this lane's output column (0..127)
    const int sx = (n & 7) << 4;

    // preload B fragments: 8 k-slices across the 2 k-halves (issued first)
    bf16x8 bfr[8];
#pragma unroll
    for (int h = 0; h < 2; ++h)
#pragma unroll
        for (int kst = 0; kst < 4; ++kst)
            bfr[h * 4 + kst] = *(const bf16x8*)((const char*)img2 + h * 32768 + n * 256 + ((kst * 64 + lk * 16) ^ sx));

    // BN1 coefficients from 16 replicas
    if (tid < 256) {
        float s = 0.f, q = 0.f;
#pragma unroll
        for (int r = 0; r < 16; ++r) { s += part1[r * 512 + tid]; q += part1[r * 512 + 256 + tid]; }
        float mu = s * INV_B;
        float var = fmaf(q, INV_B, -mu * mu);
        float rs = rsqrtf(var + BN_EPS_C);
        float a = g1[tid] * rs;
        a1s[tid] = a;
        c1s[tid] = fmaf(-mu, a, be1[tid]);
    }
    __syncthreads();

    // stage A with BN affine (linear copy + value transform)
#pragma unroll
    for (int it = 0; it < 2; ++it) {
        int a = (it * 512 + tid) * 16;
        int r = a >> 9, ks = a & 511;
        int k0 = (ks ^ ((r & 7) << 4)) >> 1;
        bf16x8 hv = *(const bf16x8*)((const char*)h1s + (size_t)bid * 16384 + a);
        bf16x8 sv;
#pragma unroll
        for (int j = 0; j < 8; ++j) {
            float f = bf2f((unsigned short)hv[j]);
            f = fmaf(a1s[k0 + j], f, c1s[k0 + j]);
            sv[j] = (short)f2bf(f);
        }
        *(bf16x8*)(As + a) = sv;
    }
    __syncthreads();

    f32x4 acc[2];
    acc[0] = (f32x4){0.f, 0.f, 0.f, 0.f};
    acc[1] = (f32x4){0.f, 0.f, 0.f, 0.f};
#pragma unroll
    for (int k8 = 0; k8 < 8; ++k8) {
        int kb = (k8 * 64 + lk * 16) ^ ((lr & 7) << 4);   // (16+lr)&7 == lr&7
        bf16x8 a0 = *(const bf16x8*)(As + lr * 512 + kb);
        bf16x8 a1v = *(const bf16x8*)(As + (16 + lr) * 512 + kb);
        acc[0] = __builtin_amdgcn_mfma_f32_16x16x32_bf16(a0, bfr[k8], acc[0], 0, 0, 0);
        acc[1] = __builtin_amdgcn_mfma_f32_16x16x32_bf16(a1v, bfr[k8], acc[1], 0, 0, 0);
    }

    // epilogue
    {
        float bias = b2[n];
        float s = 0.f, q = 0.f;
#pragma unroll
        for (int mi = 0; mi < 2; ++mi)
#pragma unroll
            for (int reg = 0; reg < 4; ++reg) {
                int rl = mi * 16 + lk * 4 + reg;
                float v = fmaxf(acc[mi][reg] + bias, 0.f);
                unsigned short hb = f2bf(v);
                float vr = bf2f(hb);
                s += vr; q += vr * vr;
                *(unsigned short*)(Bnc + swz256(rl, n * 2)) = hb;
            }
        s += __shfl_xor(s, 16); s += __shfl_xor(s, 32);
        q += __shfl_xor(q, 16); q += __shfl_xor(q, 32);
        if (lk == 0) { sstat[n] = s; sstat[128 + n] = q; }
    }
    __syncthreads();

    // dump 8 KB tile + stats replica add
    *(bf16x8*)((char*)h2s + (size_t)bid * 8192 + tid * 16) = *(const bf16x8*)(Bnc + tid * 16);
    if (tid < 256) atomicAdd(&part2[(size_t)(bid & 15) * 256 + tid], sstat[tid]);
}

// ---------------------------------------------------------------------------
// K3: BN2 folded into W3; per-row dot on h2s image (swizzle-aware reads)
//     + wide gather + sigmoid. 256 blocks x 64 rows.
// ---------------------------------------------------------------------------
__global__ __launch_bounds__(256, 2) void wd_k3(
    const int* __restrict__ ui, const int* __restrict__ ii,
    const float* __restrict__ wide_w, const float* __restrict__ wide_b,
    const unsigned short* __restrict__ h2s, const float* __restrict__ part2,
    const float* __restrict__ g2, const float* __restrict__ be2,
    const float* __restrict__ W3, const float* __restrict__ b3,
    float* __restrict__ out)
{
    __shared__ float af[128], cf[128];
    const int tid = threadIdx.x, bid = blockIdx.x;
    const int r = tid >> 2, kq = tid & 3;
    const int row = bid * 64 + r;

    float wide = 0.f;
    if (kq == 0) wide = wide_w[ui[row]] + wide_w[NUM_USERS_C + ii[row]];

    if (tid < 128) {
        float s = 0.f, q = 0.f;
#pragma unroll
        for (int rr = 0; rr < 16; ++rr) { s += part2[rr * 256 + tid]; q += part2[rr * 256 + 128 + tid]; }
        float mu = s * INV_B;
        float var = fmaf(q, INV_B, -mu * mu);
        float rs = rsqrtf(var + BN_EPS_C);
        float a = g2[tid] * rs;
        float c = fmaf(-mu, a, be2[tid]);
        float w3 = W3[tid];
        af[tid] = a * w3;
        cf[tid] = c * w3;
    }
    __syncthreads();

    const int tile = row >> 5, rin = row & 31;
    const char* tb = (const char*)h2s + (size_t)tile * 8192 + rin * 256;
    float acc = 0.f;
#pragma unroll
    for (int j = 0; j < 4; ++j) {
        int ks = (kq * 64 + j * 16) ^ ((rin & 7) << 4);
        bf16x8 hv = *(const bf16x8*)(tb + ks);
#pragma unroll
        for (int e = 0; e < 8; ++e) {
            float h = bf2f((unsigned short)hv[e]);
            int k = kq * 32 + j * 8 + e;
            acc += fmaf(h, af[k], cf[k]);
        }
    }
    acc += __shfl_xor(acc, 1);
    acc += __shfl_xor(acc, 2);
    if (kq == 0) {
        float logit = acc + b3[0] + wide_b[0] + wide;
        out[row] = 1.f / (1.f + expf(-logit));
    }
}

extern "C" void kernel_launch(void* const* d_in, const int* in_sizes, int n_in,
                              void* d_out, int out_size, void* d_ws, size_t ws_size,
                              hipStream_t stream)
{
    const int*   ui     = (const int*)d_in[0];
    const int*   ii     = (const int*)d_in[1];
    const float* wide_w = (const float*)d_in[2];
    const float* wide_b = (const float*)d_in[3];
    const float* utab   = (const float*)d_in[4];
    const float* itab   = (const float*)d_in[5];
    const float* W1     = (const float*)d_in[6];
    const float* b1     = (const float*)d_in[7];
    const float* g1     = (const float*)d_in[8];
    const float* be1    = (const float*)d_in[9];
    const float* W2     = (const float*)d_in[10];
    const float* b2     = (const float*)d_in[11];
    const float* g2     = (const float*)d_in[12];
    const float* be2    = (const float*)d_in[13];
    const float* W3     = (const float*)d_in[14];
    const float* b3     = (const float*)d_in[15];
    float* outp = (float*)d_out;

    char* base = (char*)d_ws;
    float* part1 = (float*)base;                                   // 16*512 f32
    float* part2 = (float*)(base + 16 * 512 * 4);                  // 16*256 f32
    unsigned short* img1 = (unsigned short*)(base + 49152);        // 64 KB
    unsigned short* img2 = (unsigned short*)(base + 49152 + 65536);
    unsigned short* h1s  = (unsigned short*)(base + 49152 + 131072);              // 8 MB
    unsigned short* h2s  = (unsigned short*)(base + 49152 + 131072 + (size_t)512 * 16384);

    wd_k0<<<48, 256, 0, stream>>>(W1, W2, img1, img2, part1);
    wd_k1<<<512, 512, 0, stream>>>(ui, ii, utab, itab, img1, b1, h1s, part1);
    wd_k2<<<512, 512, 0, stream>>>(h1s, part1, g1, be1, img2, b2, h2s, part2);
    wd_k3<<<256, 256, 0, stream>>>(ui, ii, wide_w, wide_b, h2s, part2, g2, be2, W3, b3, outp);
}